// Round 19
// baseline (127.405 us; speedup 1.0000x reference)
//
#include <hip/hip_runtime.h>
#include <hip/hip_bf16.h>
#include <stdint.h>

typedef __attribute__((ext_vector_type(8))) short bf16x8;
typedef __attribute__((ext_vector_type(8))) unsigned short u16x8;
typedef __attribute__((ext_vector_type(4))) float f32x4;
typedef __attribute__((ext_vector_type(16))) float f32x16;

#define DEV __device__ __forceinline__

DEV f32x4 mfma16(bf16x8 a, bf16x8 b, f32x4 c) {
  return __builtin_amdgcn_mfma_f32_16x16x32_bf16(a, b, c, 0, 0, 0);
}

DEV f32x16 mfma32(bf16x8 a, bf16x8 b, f32x16 c) {
  return __builtin_amdgcn_mfma_f32_32x32x16_bf16(a, b, c, 0, 0, 0);
}

DEV void gload_lds16(const void* g, void* l) {
  __builtin_amdgcn_global_load_lds(
      (__attribute__((address_space(1))) void*)(g),
      (__attribute__((address_space(3))) void*)(l), 16, 0, 0);
}

DEV unsigned short f2bf(float f) {
  __hip_bfloat16 h = __float2bfloat16(f);
  return __builtin_bit_cast(unsigned short, h);
}

// ------------- convert fp32 -> bf16: x + 4 weight mats into contiguous ws ---
__global__ __launch_bounds__(256) void convert_all(
    const float4* __restrict__ s0, const float4* __restrict__ s1,
    const float4* __restrict__ s2, const float4* __restrict__ s3,
    const float4* __restrict__ s4, ushort4* __restrict__ dst)
{
  const int n0 = 1048576, n1 = 196608, n3 = 65536;
  int i = blockIdx.x * 256 + threadIdx.x;
  const float4* s; int off;
  if (i < n0)                 { s = s0; off = 0; }
  else if (i < n0 + n1)       { s = s1; off = n0; }
  else if (i < n0 + 2*n1)     { s = s2; off = n0 + n1; }
  else if (i < n0 + 2*n1+n3)  { s = s3; off = n0 + 2*n1; }
  else                        { s = s4; off = n0 + 2*n1 + n3; }
  float4 v = s[i - off];
  ushort4 o;
  o.x = f2bf(v.x); o.y = f2bf(v.y); o.z = f2bf(v.z); o.w = f2bf(v.w);
  dst[i] = o;
}

// ---- 512-thread 2-phase GEMM skeleton --------------------------------------
#define GEMM_STAGE(Ap, Wp, k0v, bufi)                                          \
  {                                                                            \
    _Pragma("unroll")                                                          \
    for (int is = 0; is < 2; ++is) {                                           \
      const int row = is*64 + (t >> 3);                                        \
      const int slot = (t & 7) ^ (row & 7);                                    \
      gload_lds16((Ap) + (long)(m0 + row)*K + (k0v) + slot*8,                  \
                  (char*)&As[bufi][0] + (is*512 + t)*16);                      \
      gload_lds16((Wp) + (long)(n0 + row)*K + (k0v) + slot*8,                  \
                  (char*)&Ws[bufi][0] + (is*512 + t)*16);                      \
    }                                                                          \
  }

#define GEMM_COMPUTE(cur, NJ, WCMUL)                                           \
  {                                                                            \
    const char* Apl = (const char*)&As[cur][0];                                \
    const char* Wpl = (const char*)&Ws[cur][0];                                \
    __builtin_amdgcn_s_setprio(1);                                             \
    _Pragma("unroll")                                                          \
    for (int kk = 0; kk < 2; ++kk) {                                           \
      bf16x8 af[4], wf[NJ];                                                    \
      _Pragma("unroll")                                                        \
      for (int i = 0; i < 4; ++i) {                                            \
        const int row = wr*64 + i*16 + l16;                                    \
        const int slot = (kk*4 + g16) ^ (row & 7);                             \
        af[i] = *(const bf16x8*)(Apl + row*128 + slot*16);                     \
      }                                                                        \
      _Pragma("unroll")                                                        \
      for (int j = 0; j < NJ; ++j) {                                           \
        const int row = wc*WCMUL + j*16 + l16;                                 \
        const int slot = (kk*4 + g16) ^ (row & 7);                             \
        wf[j] = *(const bf16x8*)(Wpl + row*128 + slot*16);                     \
      }                                                                        \
      _Pragma("unroll")                                                        \
      for (int i = 0; i < 4; ++i)                                              \
        _Pragma("unroll")                                                      \
        for (int j = 0; j < NJ; ++j)                                           \
          acc[i][j] = mfma16(af[i], wf[j], acc[i][j]);                         \
    }                                                                          \
    __builtin_amdgcn_s_setprio(0);                                             \
  }

// ------------- merged QKV GEMM: XCD-partitioned (0-3 global, 4-7 local) ----
__global__ __launch_bounds__(512) void gemm_qkv(
    const __hip_bfloat16* __restrict__ A0,
    const __hip_bfloat16* __restrict__ Wg, const float* __restrict__ bg,
    const __hip_bfloat16* __restrict__ Wl, const float* __restrict__ bl,
    __hip_bfloat16* __restrict__ qkg, __hip_bfloat16* __restrict__ vtg,
    __hip_bfloat16* __restrict__ qkl, __hip_bfloat16* __restrict__ vtl,
    int M, int N, int K)
{
  __shared__ __attribute__((aligned(16))) char SMEM[65536];
  __hip_bfloat16 (*As)[8192] = (__hip_bfloat16(*)[8192])SMEM;
  __hip_bfloat16 (*Ws)[8192] = (__hip_bfloat16(*)[8192])(SMEM + 32768);
  const int t = threadIdx.x;
  const int lane = t & 63, wid = t >> 6;
  const int g16 = lane >> 4, l16 = lane & 15;
  const int wr = wid >> 2, wc = wid & 3;
  const int bid = blockIdx.x;
  const int xcd = bid & 7, seq = bid >> 3;
  const int sel = xcd >= 4;
  const int xh = xcd & 3;
  const int m0 = (xh*16 + (seq & 15)) * 128;
  const int n0 = (seq >> 4) * 128;
  const __hip_bfloat16* W0 = sel ? Wl : Wg;
  const float* b0 = sel ? bl : bg;
  __hip_bfloat16* qkp = sel ? qkl : qkg;
  __hip_bfloat16* vtp = sel ? vtl : vtg;

  f32x4 acc[4][2] = {};
  const int nks = K >> 6;

  GEMM_STAGE(A0, W0, 0, 0)
  for (int step = 0; step < nks; ++step) {
    const int cur = step & 1;
    if (step + 1 < nks) {
      GEMM_STAGE(A0, W0, (step+1) << 6, cur ^ 1)
      asm volatile("s_waitcnt vmcnt(4)" ::: "memory");
    } else {
      asm volatile("s_waitcnt vmcnt(0)" ::: "memory");
    }
    __builtin_amdgcn_s_barrier();
    asm volatile("" ::: "memory");
    GEMM_COMPUTE(cur, 2, 32)
    asm volatile("" ::: "memory");
    __builtin_amdgcn_s_barrier();
  }

  if (n0 < 1024) {
#pragma unroll
    for (int i = 0; i < 4; ++i) {
      const int gr = m0 + wr*64 + i*16 + g16*4;
#pragma unroll
      for (int j = 0; j < 2; ++j) {
        const int gc = n0 + wc*32 + j*16 + l16;
        const float bias = b0[gc];
        const float scl = (gc >= 512) ? 0.180336880f : 1.0f;  // 0.125*log2(e)
#pragma unroll
        for (int r = 0; r < 4; ++r)
          qkp[(long)(gr + r)*1024 + gc] =
              __float2bfloat16((acc[i][j][r] + bias) * scl);
      }
    }
  } else {
    const int n0l = n0 - 1024;
    short* T = (short*)SMEM;
#pragma unroll
    for (int i = 0; i < 4; ++i) {
      const int sl = wr*16 + i*4 + g16;
#pragma unroll
      for (int j = 0; j < 2; ++j) {
        const int gcl = wc*32 + j*16 + l16;
        const float bias = b0[n0 + gcl];
#pragma unroll
        for (int r = 0; r < 4; ++r)
          T[gcl*136 + r*32 + sl] = (short)f2bf(acc[i][j][r] + bias);
      }
    }
    __syncthreads();
    const int d = t & 127, b4 = t >> 7;
    __hip_bfloat16* dst = vtp + ((long)(b4*512 + n0l + d))*2048 + (m0 >> 2);
#pragma unroll
    for (int k = 0; k < 4; ++k) {
      u16x8 v = *(const u16x8*)(T + d*136 + b4*32 + k*8);
      *(u16x8*)(dst + k*8) = v;
    }
  }
}

// ------------- final GEMM: 128x64 tile, 512 blocks (2/CU) ------------------
__global__ __launch_bounds__(512) void gemm_out(
    const __hip_bfloat16* __restrict__ A0, const __hip_bfloat16* __restrict__ W0,
    const float* __restrict__ b0,
    const __hip_bfloat16* __restrict__ A1, const __hip_bfloat16* __restrict__ W1,
    const float* __restrict__ b1,
    float* __restrict__ Cout, int M, int N, int K)
{
  __shared__ __attribute__((aligned(16))) __hip_bfloat16 As[2][128*64];
  __shared__ __attribute__((aligned(16))) __hip_bfloat16 Ws[2][64*64];
  const int t = threadIdx.x;
  const int lane = t & 63, wid = t >> 6;
  const int g16 = lane >> 4, l16 = lane & 15;
  const int wr = wid >> 2, wc = wid & 3;
  const int bid = blockIdx.x;
  const int xcd = bid & 7, pos = bid >> 3;
  const int m0 = (xcd*8 + (pos & 7)) * 128, n0 = (pos >> 3) * 64;

  f32x4 acc[4][1] = {};
  const int nks = K >> 6;
  const int NS = 2*nks;

#define OUT_STAGE(Ap, Wp, k0v, bufi)                                           \
  {                                                                            \
    _Pragma("unroll")                                                          \
    for (int is = 0; is < 2; ++is) {                                           \
      const int row = is*64 + (t >> 3);                                        \
      const int slot = (t & 7) ^ (row & 7);                                    \
      gload_lds16((Ap) + (long)(m0 + row)*K + (k0v) + slot*8,                  \
                  (char*)&As[bufi][0] + (is*512 + t)*16);                      \
    }                                                                          \
    {                                                                          \
      const int row = t >> 3;                                                  \
      const int slot = (t & 7) ^ (row & 7);                                    \
      gload_lds16((Wp) + (long)(n0 + row)*K + (k0v) + slot*8,                  \
                  (char*)&Ws[bufi][0] + t*16);                                 \
    }                                                                          \
  }

  OUT_STAGE(A0, W0, 0, 0)
  for (int step = 0; step < NS; ++step) {
    const int cur = step & 1;
    if (step + 1 < NS) {
      const int nstep = step + 1;
      const __hip_bfloat16* Ap = (nstep >= nks) ? A1 : A0;
      const __hip_bfloat16* Wp = (nstep >= nks) ? W1 : W0;
      const int k0 = ((nstep >= nks) ? (nstep - nks) : nstep) << 6;
      OUT_STAGE(Ap, Wp, k0, cur ^ 1)
      asm volatile("s_waitcnt vmcnt(3)" ::: "memory");
    } else {
      asm volatile("s_waitcnt vmcnt(0)" ::: "memory");
    }
    __builtin_amdgcn_s_barrier();
    asm volatile("" ::: "memory");
    GEMM_COMPUTE(cur, 1, 16)
    asm volatile("" ::: "memory");
    __builtin_amdgcn_s_barrier();
  }

#pragma unroll
  for (int i = 0; i < 4; ++i) {
    const int gr = m0 + wr*64 + i*16 + g16*4;
    const int gc = n0 + wc*16 + l16;
    const float bias = b0[gc] + b1[gc];
#pragma unroll
    for (int r = 0; r < 4; ++r)
      Cout[(long)(gr + r)*N + gc] = acc[i][0][r] + bias;
  }
}

// ------------- GLOBAL flash: 256 q/block, 8 waves x 32 q, 32x32 MFMA -------
// qk: [(s*B+b)*1024 + {0:Q, 512:K*c2} + head*64 + d]; vt: [b*512+head*64+d][s].
// S^T = mfma32(K, Q): lane (hf=lane>>5, l32=lane&31) owns q-col l32 with kv
// rows (r&3)+8*(r>>2)+4*hf per 32-block. RAW softmax (K pre-scaled). PV
// B-frag (P) rebuilt IN-REGISTER via 2x v_permlane32_swap per k-step:
// w0,w2 = swap(A0,B0); w1,w3 = swap(A1,B1) where A=group(2q2),B=group(2q2+1)
// packs of the lane's own p-values. No P-LDS. l = in-lane sum + 1 shfl.
// 32x32 gives 2x FLOP per LDS byte vs 16x16 -> halves the LDS-BW wall.
__global__ __launch_bounds__(512) void flash_g256(
    const __hip_bfloat16* __restrict__ qk, const __hip_bfloat16* __restrict__ vt,
    __hip_bfloat16* __restrict__ outg, int S, int B)
{
  const int t = threadIdx.x, lane = t & 63, w = t >> 6;
  const int l32 = lane & 31, hf = lane >> 5;
  const int id = blockIdx.x;                // 256 blocks
  const int xcd = id & 7, seq = id >> 3;
  const int bh = xcd + 8*(seq & 3);
  const int qt = seq >> 2;                  // 0..7
  const int b = bh >> 3, head = bh & 7;
  const int q0 = qt * 256;
  const int nkt = S >> 6;                   // 32
  const int vtb = bh * 64;

  __shared__ __attribute__((aligned(16))) __hip_bfloat16 Kb[2][64*64];
  __shared__ __attribute__((aligned(16))) __hip_bfloat16 Vb[2][64*64];

  const int qw = q0 + w*32 + l32;
  bf16x8 qa[4];
  {
    const __hip_bfloat16* qp = qk + ((long)qw*B + b)*1024 + head*64 + hf*8;
#pragma unroll
    for (int ks = 0; ks < 4; ++ks)
      qa[ks] = *(const bf16x8*)(const void*)(qp + ks*16);
  }

  f32x16 oacc[2] = {};
  float lsum = 0.f;

#define GSTAGE(tile, bufi)                                                     \
  {                                                                            \
    const int kvs_ = (tile)*64;                                                \
    const int row_ = t >> 3;                                                   \
    const int sl_ = (t & 7) ^ (row_ & 7);                                      \
    gload_lds16(qk + ((long)(kvs_+row_)*B + b)*1024 + 512 + head*64 + sl_*8,   \
                (char*)&Kb[bufi][0] + t*16);                                   \
    gload_lds16(vt + (long)(vtb + row_)*2048 + kvs_ + sl_*8,                   \
                (char*)&Vb[bufi][0] + t*16);                                   \
  }

  GSTAGE(0, 0)

  for (int kt = 0; kt < nkt; ++kt) {
    const int cur = kt & 1;
    if (kt + 1 < nkt) {
      GSTAGE(kt + 1, cur ^ 1)
      asm volatile("s_waitcnt vmcnt(2)" ::: "memory");
    } else {
      asm volatile("s_waitcnt vmcnt(0)" ::: "memory");
    }
    __builtin_amdgcn_s_barrier();
    asm volatile("" ::: "memory");

    // --- S^T = K @ Q^T : sacc[jb] covers kv-block jb (32 kv) x 32 q -------
    f32x16 sacc[2] = {};
    const char* Kp = (const char*)&Kb[cur][0];
    __builtin_amdgcn_s_setprio(1);
#pragma unroll
    for (int ks = 0; ks < 4; ++ks)
#pragma unroll
      for (int jb = 0; jb < 2; ++jb) {
        const int row = jb*32 + l32;
        const int slot = (ks*2 + hf) ^ (row & 7);
        bf16x8 kf = *(const bf16x8*)(Kp + row*128 + slot*16);
        sacc[jb] = mfma32(kf, qa[ks], sacc[jb]);
      }
    __builtin_amdgcn_s_setprio(0);

    // --- raw softmax numerators, packed into per-group u32 pairs ----------
    unsigned pk[2][8];
#pragma unroll
    for (int jb = 0; jb < 2; ++jb)
#pragma unroll
      for (int rg = 0; rg < 4; ++rg)
#pragma unroll
        for (int hv = 0; hv < 2; ++hv) {
          const float p0 = __builtin_amdgcn_exp2f(sacc[jb][rg*4 + hv*2]);
          const float p1 = __builtin_amdgcn_exp2f(sacc[jb][rg*4 + hv*2 + 1]);
          lsum += p0 + p1;
          pk[jb][rg*2 + hv] =
              (unsigned)f2bf(p0) | ((unsigned)f2bf(p1) << 16);
        }

    // --- O^T += V^T @ P^T : P B-frags via permlane32_swap -----------------
    const char* Vp = (const char*)&Vb[cur][0];
    __builtin_amdgcn_s_setprio(1);
#pragma unroll
    for (int ks = 0; ks < 4; ++ks) {
      const int q2 = ks & 1, jb = ks >> 1;
      unsigned w0 = pk[jb][4*q2 + 0], w2v = pk[jb][4*q2 + 2];
      asm volatile("v_permlane32_swap_b32 %0, %1" : "+v"(w0), "+v"(w2v));
      unsigned w1 = pk[jb][4*q2 + 1], w3v = pk[jb][4*q2 + 3];
      asm volatile("v_permlane32_swap_b32 %0, %1" : "+v"(w1), "+v"(w3v));
      union { unsigned u[4]; bf16x8 v; } pb;
      pb.u[0] = w0; pb.u[1] = w1; pb.u[2] = w2v; pb.u[3] = w3v;
#pragma unroll
      for (int db = 0; db < 2; ++db) {
        const int row = db*32 + l32;
        const int slot = (ks*2 + hf) ^ (row & 7);
        bf16x8 vf = *(const bf16x8*)(Vp + row*128 + slot*16);
        oacc[db] = mfma32(vf, pb.v, oacc[db]);
      }
    }
    __builtin_amdgcn_s_setprio(0);

    asm volatile("" ::: "memory");
    __builtin_amdgcn_s_barrier();
  }

  // --- epilogue: O^T[d][q=l32]; d = db*32 + 8*rq + 4*hf + i ---------------
  lsum += __shfl_xor(lsum, 32, 64);
  const float inv = 1.f / lsum;
  const long base = ((long)qw*B + b)*512 + head*64;
#pragma unroll
  for (int db = 0; db < 2; ++db)
#pragma unroll
    for (int rq = 0; rq < 4; ++rq) {
      ushort4 pkk;
      pkk.x = f2bf(oacc[db][rq*4 + 0]*inv);
      pkk.y = f2bf(oacc[db][rq*4 + 1]*inv);
      pkk.z = f2bf(oacc[db][rq*4 + 2]*inv);
      pkk.w = f2bf(oacc[db][rq*4 + 3]*inv);
      *(ushort4*)(outg + base + db*32 + rq*8 + hf*4) = pkk;
    }
}

// ------------- LOCAL flash: validated 16x16 kernel (nkt=2 per block) -------
__global__ __launch_bounds__(512) void flash_all(
    const __hip_bfloat16* __restrict__ qkg, const __hip_bfloat16* __restrict__ vtg,
    __hip_bfloat16* __restrict__ outg,
    const __hip_bfloat16* __restrict__ qkl, const __hip_bfloat16* __restrict__ vtl,
    __hip_bfloat16* __restrict__ outl,
    const int* __restrict__ wptr, int S, int B, int blkoff)
{
  const int t = threadIdx.x, lane = t & 63, w = t >> 6;
  const int g16 = lane >> 4, l16 = lane & 15;
  const int gid = blockIdx.x + blkoff;
  const int isl = gid >= 512;
  const int id = gid & 511;
  const __hip_bfloat16* qk = isl ? qkl : qkg;
  const __hip_bfloat16* vt = isl ? vtl : vtg;
  __hip_bfloat16* outb = isl ? outl : outg;
  const int Wn = isl ? wptr[0] : S;
  const int xcd = id & 7, seq = id >> 3;
  const int bh = xcd + 8*(seq & 3);
  const int qt = seq >> 2;
  const int b = bh >> 3, h = bh & 7;
  const int q0 = qt * 128;
  const int kv0 = (q0 / Wn) * Wn;
  const int nkt = Wn >> 6;
  const int vtb = bh * 64;

  __shared__ __attribute__((aligned(16))) __hip_bfloat16 Kb[2][64*64];
  __shared__ __attribute__((aligned(16))) __hip_bfloat16 Vb[2][64*64];
  __shared__ __attribute__((aligned(16))) short Pl[8][16*72];

  const int qrow = q0 + w*16 + l16;
  bf16x8 qa[2];
  {
    const __hip_bfloat16* qp = qk + ((long)qrow*B + b)*1024 + h*64 + g16*8;
    qa[0] = *(const bf16x8*)(const void*)qp;
    qa[1] = *(const bf16x8*)(const void*)(qp + 32);
  }
  bf16x8 aones;
#pragma unroll
  for (int e = 0; e < 8; ++e) aones[e] = (short)0x3F80;

  f32x4 o[4] = {};
  f32x4 ol = {};

#define STAGE(tile, bufi)                                                      \
  {                                                                            \
    const int kvs_ = kv0 + (tile)*64;                                          \
    const int row_ = t >> 3;                                                   \
    const int sl_ = (t & 7) ^ (row_ & 7);                                      \
    gload_lds16(qk + ((long)(kvs_+row_)*B + b)*1024 + 512 + h*64 + sl_*8,      \
                (char*)&Kb[bufi][0] + t*16);                                   \
    gload_lds16(vt + (long)(vtb + row_)*2048 + kvs_ + sl_*8,                   \
                (char*)&Vb[bufi][0] + t*16);                                   \
  }

  STAGE(0, 0)

  for (int kt = 0; kt < nkt; ++kt) {
    const int cur = kt & 1;
    if (kt + 1 < nkt) {
      STAGE(kt + 1, cur ^ 1)
      asm volatile("s_waitcnt vmcnt(2)" ::: "memory");
    } else {
      asm volatile("s_waitcnt vmcnt(0)" ::: "memory");
    }
    __builtin_amdgcn_s_barrier();
    asm volatile("" ::: "memory");

    f32x4 s[4] = {};
    const char* Kp = (const char*)&Kb[cur][0];
    __builtin_amdgcn_s_setprio(1);
#pragma unroll
    for (int kk = 0; kk < 2; ++kk)
#pragma unroll
      for (int j = 0; j < 4; ++j) {
        const int row = j*16 + l16;
        const int slot = (kk*4 + g16) ^ (row & 7);
        bf16x8 kf = *(const bf16x8*)(Kp + row*128 + slot*16);
        s[j] = mfma16(kf, qa[kk], s[j]);
      }
    __builtin_amdgcn_s_setprio(0);

    short* Pw = &Pl[w][0];
#pragma unroll
    for (int j = 0; j < 4; ++j) {
      short4 pk4;
      pk4.x = (short)f2bf(__builtin_amdgcn_exp2f(s[j][0]));
      pk4.y = (short)f2bf(__builtin_amdgcn_exp2f(s[j][1]));
      pk4.z = (short)f2bf(__builtin_amdgcn_exp2f(s[j][2]));
      pk4.w = (short)f2bf(__builtin_amdgcn_exp2f(s[j][3]));
      *(short4*)(Pw + l16*72 + j*16 + g16*4) = pk4;
    }

    __builtin_amdgcn_s_setprio(1);
#pragma unroll
    for (int kk = 0; kk < 2; ++kk) {
      bf16x8 pf = *(const bf16x8*)(Pw + l16*72 + kk*32 + g16*8);
      ol = mfma16(aones, pf, ol);
#pragma unroll
      for (int dblk = 0; dblk < 4; ++dblk) {
        const int row = dblk*16 + l16;
        const int slot = (kk*4 + g16) ^ (row & 7);
        bf16x8 vf = *(const bf16x8*)((const char*)&Vb[cur][0] + row*128 + slot*16);
        o[dblk] = mfma16(vf, pf, o[dblk]);
      }
    }
    __builtin_amdgcn_s_setprio(0);

    asm volatile("" ::: "memory");
    __builtin_amdgcn_s_barrier();
  }

  const float inv = 1.f / ol[0];
  const long obase = ((long)qrow*B + b)*512 + h*64;
#pragma unroll
  for (int dblk = 0; dblk < 4; ++dblk) {
    ushort4 pk;
    pk.x = f2bf(o[dblk][0]*inv); pk.y = f2bf(o[dblk][1]*inv);
    pk.z = f2bf(o[dblk][2]*inv); pk.w = f2bf(o[dblk][3]*inv);
    *(ushort4*)(outb + obase + dblk*16 + g16*4) = pk;
  }
}

extern "C" void kernel_launch(void* const* d_in, const int* in_sizes, int n_in,
                              void* d_out, int out_size, void* d_ws, size_t ws_size,
                              hipStream_t stream) {
  const float* x   = (const float*)d_in[0];
  const float* wig = (const float*)d_in[1];
  const float* big = (const float*)d_in[2];
  const float* wog = (const float*)d_in[3];
  const float* bog = (const float*)d_in[4];
  const float* wil = (const float*)d_in[5];
  const float* bil = (const float*)d_in[6];
  const float* wol = (const float*)d_in[7];
  const float* bol = (const float*)d_in[8];
  const int*   wsz = (const int*)d_in[9];

  char* ws = (char*)d_ws;
  __hip_bfloat16* xb    = (__hip_bfloat16*)(ws + 0);          // 8 MB (-> attn_g)
  __hip_bfloat16* wigb  = (__hip_bfloat16*)(ws + 8388608);
  __hip_bfloat16* wilb  = (__hip_bfloat16*)(ws + 9961472);
  __hip_bfloat16* wogb  = (__hip_bfloat16*)(ws + 11534336);
  __hip_bfloat16* wolb  = (__hip_bfloat16*)(ws + 12058624);
  __hip_bfloat16* qkg   = (__hip_bfloat16*)(ws + 12582912);   // 16 MB
  __hip_bfloat16* qkl   = (__hip_bfloat16*)(ws + 29360128);   // 16 MB
  __hip_bfloat16* vtg   = (__hip_bfloat16*)(ws + 46137344);   // 8 MB
  __hip_bfloat16* vtl   = (__hip_bfloat16*)(ws + 54525952);   // 8 MB (end 60 MB)
  __hip_bfloat16* attng = xb;                                  // xb dead after qkv

  const int big_ws = ws_size >= (size_t)71303168;              // 68 MB
  __hip_bfloat16* attnl = big_ws ? (__hip_bfloat16*)(ws + 62914560)
                                 : qkg;                        // safe: local runs
                                                               // after qkg is dead
  convert_all<<<6144, 256, 0, stream>>>(
      (const float4*)x, (const float4*)wig, (const float4*)wil,
      (const float4*)wog, (const float4*)wol, (ushort4*)ws);

  gemm_qkv<<<1536, 512, 0, stream>>>(xb, wigb, big, wilb, bil,
                                     qkg, vtg, qkl, vtl, 8192, 1536, 512);

  flash_g256<<<256, 512, 0, stream>>>(qkg, vtg, attng, 2048, 4);
  flash_all<<<512, 512, 0, stream>>>(qkg, vtg, attng, qkl, vtl, attnl,
                                     wsz, 2048, 4, 512);

  gemm_out<<<512, 512, 0, stream>>>(attng, wogb, bog, attnl, wolb, bol,
                                    (float*)d_out, 8192, 512, 512);
}

// Round 20
// 125.942 us; speedup vs baseline: 1.0116x; 1.0116x over previous
//
#include <hip/hip_runtime.h>
#include <hip/hip_bf16.h>
#include <stdint.h>

typedef __attribute__((ext_vector_type(8))) short bf16x8;
typedef __attribute__((ext_vector_type(8))) unsigned short u16x8;
typedef __attribute__((ext_vector_type(4))) float f32x4;
typedef __attribute__((ext_vector_type(16))) float f32x16;

#define DEV __device__ __forceinline__

DEV f32x4 mfma16(bf16x8 a, bf16x8 b, f32x4 c) {
  return __builtin_amdgcn_mfma_f32_16x16x32_bf16(a, b, c, 0, 0, 0);
}

DEV f32x16 mfma32(bf16x8 a, bf16x8 b, f32x16 c) {
  return __builtin_amdgcn_mfma_f32_32x32x16_bf16(a, b, c, 0, 0, 0);
}

DEV void gload_lds16(const void* g, void* l) {
  __builtin_amdgcn_global_load_lds(
      (__attribute__((address_space(1))) void*)(g),
      (__attribute__((address_space(3))) void*)(l), 16, 0, 0);
}

DEV unsigned short f2bf(float f) {
  __hip_bfloat16 h = __float2bfloat16(f);
  return __builtin_bit_cast(unsigned short, h);
}

DEV float bf2f(unsigned short u) {
  return __builtin_bit_cast(float, (unsigned)u << 16);
}

// ------------- convert fp32 -> bf16: x + 4 weight mats into contiguous ws ---
__global__ __launch_bounds__(256) void convert_all(
    const float4* __restrict__ s0, const float4* __restrict__ s1,
    const float4* __restrict__ s2, const float4* __restrict__ s3,
    const float4* __restrict__ s4, ushort4* __restrict__ dst)
{
  const int n0 = 1048576, n1 = 196608, n3 = 65536;
  int i = blockIdx.x * 256 + threadIdx.x;
  const float4* s; int off;
  if (i < n0)                 { s = s0; off = 0; }
  else if (i < n0 + n1)       { s = s1; off = n0; }
  else if (i < n0 + 2*n1)     { s = s2; off = n0 + n1; }
  else if (i < n0 + 2*n1+n3)  { s = s3; off = n0 + 2*n1; }
  else                        { s = s4; off = n0 + 2*n1 + n3; }
  float4 v = s[i - off];
  ushort4 o;
  o.x = f2bf(v.x); o.y = f2bf(v.y); o.z = f2bf(v.z); o.w = f2bf(v.w);
  dst[i] = o;
}

// ---- 512-thread 2-phase GEMM skeleton --------------------------------------
#define GEMM_STAGE(Ap, Wp, k0v, bufi)                                          \
  {                                                                            \
    _Pragma("unroll")                                                          \
    for (int is = 0; is < 2; ++is) {                                           \
      const int row = is*64 + (t >> 3);                                        \
      const int slot = (t & 7) ^ (row & 7);                                    \
      gload_lds16((Ap) + (long)(m0 + row)*K + (k0v) + slot*8,                  \
                  (char*)&As[bufi][0] + (is*512 + t)*16);                      \
      gload_lds16((Wp) + (long)(n0 + row)*K + (k0v) + slot*8,                  \
                  (char*)&Ws[bufi][0] + (is*512 + t)*16);                      \
    }                                                                          \
  }

#define GEMM_COMPUTE(cur, NJ, WCMUL)                                           \
  {                                                                            \
    const char* Apl = (const char*)&As[cur][0];                                \
    const char* Wpl = (const char*)&Ws[cur][0];                                \
    __builtin_amdgcn_s_setprio(1);                                             \
    _Pragma("unroll")                                                          \
    for (int kk = 0; kk < 2; ++kk) {                                           \
      bf16x8 af[4], wf[NJ];                                                    \
      _Pragma("unroll")                                                        \
      for (int i = 0; i < 4; ++i) {                                            \
        const int row = wr*64 + i*16 + l16;                                    \
        const int slot = (kk*4 + g16) ^ (row & 7);                             \
        af[i] = *(const bf16x8*)(Apl + row*128 + slot*16);                     \
      }                                                                        \
      _Pragma("unroll")                                                        \
      for (int j = 0; j < NJ; ++j) {                                           \
        const int row = wc*WCMUL + j*16 + l16;                                 \
        const int slot = (kk*4 + g16) ^ (row & 7);                             \
        wf[j] = *(const bf16x8*)(Wpl + row*128 + slot*16);                     \
      }                                                                        \
      _Pragma("unroll")                                                        \
      for (int i = 0; i < 4; ++i)                                              \
        _Pragma("unroll")                                                      \
        for (int j = 0; j < NJ; ++j)                                           \
          acc[i][j] = mfma16(af[i], wf[j], acc[i][j]);                         \
    }                                                                          \
    __builtin_amdgcn_s_setprio(0);                                             \
  }

// ------------- merged QKV GEMM: XCD-partitioned (0-3 global, 4-7 local) ----
__global__ __launch_bounds__(512) void gemm_qkv(
    const __hip_bfloat16* __restrict__ A0,
    const __hip_bfloat16* __restrict__ Wg, const float* __restrict__ bg,
    const __hip_bfloat16* __restrict__ Wl, const float* __restrict__ bl,
    __hip_bfloat16* __restrict__ qkg, __hip_bfloat16* __restrict__ vtg,
    __hip_bfloat16* __restrict__ qkl, __hip_bfloat16* __restrict__ vtl,
    int M, int N, int K)
{
  __shared__ __attribute__((aligned(16))) char SMEM[65536];
  __hip_bfloat16 (*As)[8192] = (__hip_bfloat16(*)[8192])SMEM;
  __hip_bfloat16 (*Ws)[8192] = (__hip_bfloat16(*)[8192])(SMEM + 32768);
  const int t = threadIdx.x;
  const int lane = t & 63, wid = t >> 6;
  const int g16 = lane >> 4, l16 = lane & 15;
  const int wr = wid >> 2, wc = wid & 3;
  const int bid = blockIdx.x;
  const int xcd = bid & 7, seq = bid >> 3;
  const int sel = xcd >= 4;
  const int xh = xcd & 3;
  const int m0 = (xh*16 + (seq & 15)) * 128;
  const int n0 = (seq >> 4) * 128;
  const __hip_bfloat16* W0 = sel ? Wl : Wg;
  const float* b0 = sel ? bl : bg;
  __hip_bfloat16* qkp = sel ? qkl : qkg;
  __hip_bfloat16* vtp = sel ? vtl : vtg;

  f32x4 acc[4][2] = {};
  const int nks = K >> 6;

  GEMM_STAGE(A0, W0, 0, 0)
  for (int step = 0; step < nks; ++step) {
    const int cur = step & 1;
    if (step + 1 < nks) {
      GEMM_STAGE(A0, W0, (step+1) << 6, cur ^ 1)
      asm volatile("s_waitcnt vmcnt(4)" ::: "memory");
    } else {
      asm volatile("s_waitcnt vmcnt(0)" ::: "memory");
    }
    __builtin_amdgcn_s_barrier();
    asm volatile("" ::: "memory");
    GEMM_COMPUTE(cur, 2, 32)
    asm volatile("" ::: "memory");
    __builtin_amdgcn_s_barrier();
  }

  if (n0 < 1024) {
#pragma unroll
    for (int i = 0; i < 4; ++i) {
      const int gr = m0 + wr*64 + i*16 + g16*4;
#pragma unroll
      for (int j = 0; j < 2; ++j) {
        const int gc = n0 + wc*32 + j*16 + l16;
        const float bias = b0[gc];
        const float scl = (gc >= 512) ? 0.180336880f : 1.0f;  // 0.125*log2(e)
#pragma unroll
        for (int r = 0; r < 4; ++r)
          qkp[(long)(gr + r)*1024 + gc] =
              __float2bfloat16((acc[i][j][r] + bias) * scl);
      }
    }
  } else {
    const int n0l = n0 - 1024;
    short* T = (short*)SMEM;
#pragma unroll
    for (int i = 0; i < 4; ++i) {
      const int sl = wr*16 + i*4 + g16;
#pragma unroll
      for (int j = 0; j < 2; ++j) {
        const int gcl = wc*32 + j*16 + l16;
        const float bias = b0[n0 + gcl];
#pragma unroll
        for (int r = 0; r < 4; ++r)
          T[gcl*136 + r*32 + sl] = (short)f2bf(acc[i][j][r] + bias);
      }
    }
    __syncthreads();
    const int d = t & 127, b4 = t >> 7;
    __hip_bfloat16* dst = vtp + ((long)(b4*512 + n0l + d))*2048 + (m0 >> 2);
#pragma unroll
    for (int k = 0; k < 4; ++k) {
      u16x8 v = *(const u16x8*)(T + d*136 + b4*32 + k*8);
      *(u16x8*)(dst + k*8) = v;
    }
  }
}

// ------------- final GEMM: 128x64 tile, 512 blocks (2/CU) ------------------
__global__ __launch_bounds__(512) void gemm_out(
    const __hip_bfloat16* __restrict__ A0, const __hip_bfloat16* __restrict__ W0,
    const float* __restrict__ b0,
    const __hip_bfloat16* __restrict__ A1, const __hip_bfloat16* __restrict__ W1,
    const float* __restrict__ b1,
    float* __restrict__ Cout, int M, int N, int K)
{
  __shared__ __attribute__((aligned(16))) __hip_bfloat16 As[2][128*64];
  __shared__ __attribute__((aligned(16))) __hip_bfloat16 Ws[2][64*64];
  const int t = threadIdx.x;
  const int lane = t & 63, wid = t >> 6;
  const int g16 = lane >> 4, l16 = lane & 15;
  const int wr = wid >> 2, wc = wid & 3;
  const int bid = blockIdx.x;
  const int xcd = bid & 7, pos = bid >> 3;
  const int m0 = (xcd*8 + (pos & 7)) * 128, n0 = (pos >> 3) * 64;

  f32x4 acc[4][1] = {};
  const int nks = K >> 6;
  const int NS = 2*nks;

#define OUT_STAGE(Ap, Wp, k0v, bufi)                                           \
  {                                                                            \
    _Pragma("unroll")                                                          \
    for (int is = 0; is < 2; ++is) {                                           \
      const int row = is*64 + (t >> 3);                                        \
      const int slot = (t & 7) ^ (row & 7);                                    \
      gload_lds16((Ap) + (long)(m0 + row)*K + (k0v) + slot*8,                  \
                  (char*)&As[bufi][0] + (is*512 + t)*16);                      \
    }                                                                          \
    {                                                                          \
      const int row = t >> 3;                                                  \
      const int slot = (t & 7) ^ (row & 7);                                    \
      gload_lds16((Wp) + (long)(n0 + row)*K + (k0v) + slot*8,                  \
                  (char*)&Ws[bufi][0] + t*16);                                 \
    }                                                                          \
  }

  OUT_STAGE(A0, W0, 0, 0)
  for (int step = 0; step < NS; ++step) {
    const int cur = step & 1;
    if (step + 1 < NS) {
      const int nstep = step + 1;
      const __hip_bfloat16* Ap = (nstep >= nks) ? A1 : A0;
      const __hip_bfloat16* Wp = (nstep >= nks) ? W1 : W0;
      const int k0 = ((nstep >= nks) ? (nstep - nks) : nstep) << 6;
      OUT_STAGE(Ap, Wp, k0, cur ^ 1)
      asm volatile("s_waitcnt vmcnt(3)" ::: "memory");
    } else {
      asm volatile("s_waitcnt vmcnt(0)" ::: "memory");
    }
    __builtin_amdgcn_s_barrier();
    asm volatile("" ::: "memory");
    GEMM_COMPUTE(cur, 1, 16)
    asm volatile("" ::: "memory");
    __builtin_amdgcn_s_barrier();
  }

#pragma unroll
  for (int i = 0; i < 4; ++i) {
    const int gr = m0 + wr*64 + i*16 + g16*4;
    const int gc = n0 + wc*16 + l16;
    const float bias = b0[gc] + b1[gc];
#pragma unroll
    for (int r = 0; r < 4; ++r)
      Cout[(long)(gr + r)*N + gc] = acc[i][0][r] + bias;
  }
}

// ------------- GLOBAL flash: 32x32 MFMA, SPLIT-KV (2 halves), 512 blocks ---
// HW-validated body (R19): S^T = mfma32(K,Q), P in-register via
// v_permlane32_swap, raw softmax. Now each block sweeps HALF the kv (16
// tiles) -> 2 blocks/CU, 16 waves/CU (was 8): hides the latency-bound
// critical path g256 exposed. Writes UNNORMALIZED O + l; exact merge after.
__global__ __launch_bounds__(512) void flash_g256(
    const __hip_bfloat16* __restrict__ qk, const __hip_bfloat16* __restrict__ vt,
    __hip_bfloat16* __restrict__ oa, __hip_bfloat16* __restrict__ ob,
    float* __restrict__ la, float* __restrict__ lb, int S, int B)
{
  const int t = threadIdx.x, lane = t & 63, w = t >> 6;
  const int l32 = lane & 31, hf = lane >> 5;
  const int half = blockIdx.x >> 8;         // 0 or 1
  const int id = blockIdx.x & 255;
  const int xcd = id & 7, seq = id >> 3;
  const int bh = xcd + 8*(seq & 3);
  const int qt = seq >> 2;                  // 0..7
  const int b = bh >> 3, head = bh & 7;
  const int q0 = qt * 256;
  const int kv0 = half * (S >> 1);
  const int nkt = S >> 7;                   // 16 tiles of 64 kv
  const int vtb = bh * 64;

  __shared__ __attribute__((aligned(16))) __hip_bfloat16 Kb[2][64*64];
  __shared__ __attribute__((aligned(16))) __hip_bfloat16 Vb[2][64*64];

  const int qw = q0 + w*32 + l32;
  bf16x8 qa[4];
  {
    const __hip_bfloat16* qp = qk + ((long)qw*B + b)*1024 + head*64 + hf*8;
#pragma unroll
    for (int ks = 0; ks < 4; ++ks)
      qa[ks] = *(const bf16x8*)(const void*)(qp + ks*16);
  }

  f32x16 oacc[2] = {};
  float lsum = 0.f;

#define GSTAGE(tile, bufi)                                                     \
  {                                                                            \
    const int kvs_ = kv0 + (tile)*64;                                          \
    const int row_ = t >> 3;                                                   \
    const int sl_ = (t & 7) ^ (row_ & 7);                                      \
    gload_lds16(qk + ((long)(kvs_+row_)*B + b)*1024 + 512 + head*64 + sl_*8,   \
                (char*)&Kb[bufi][0] + t*16);                                   \
    gload_lds16(vt + (long)(vtb + row_)*2048 + kvs_ + sl_*8,                   \
                (char*)&Vb[bufi][0] + t*16);                                   \
  }

  GSTAGE(0, 0)

  for (int kt = 0; kt < nkt; ++kt) {
    const int cur = kt & 1;
    if (kt + 1 < nkt) {
      GSTAGE(kt + 1, cur ^ 1)
      asm volatile("s_waitcnt vmcnt(2)" ::: "memory");
    } else {
      asm volatile("s_waitcnt vmcnt(0)" ::: "memory");
    }
    __builtin_amdgcn_s_barrier();
    asm volatile("" ::: "memory");

    // --- S^T = K @ Q^T ----------------------------------------------------
    f32x16 sacc[2] = {};
    const char* Kp = (const char*)&Kb[cur][0];
    __builtin_amdgcn_s_setprio(1);
#pragma unroll
    for (int ks = 0; ks < 4; ++ks)
#pragma unroll
      for (int jb = 0; jb < 2; ++jb) {
        const int row = jb*32 + l32;
        const int slot = (ks*2 + hf) ^ (row & 7);
        bf16x8 kf = *(const bf16x8*)(Kp + row*128 + slot*16);
        sacc[jb] = mfma32(kf, qa[ks], sacc[jb]);
      }
    __builtin_amdgcn_s_setprio(0);

    // --- raw softmax numerators, packed into per-group u32 pairs ----------
    unsigned pk[2][8];
#pragma unroll
    for (int jb = 0; jb < 2; ++jb)
#pragma unroll
      for (int rg = 0; rg < 4; ++rg)
#pragma unroll
        for (int hv = 0; hv < 2; ++hv) {
          const float p0 = __builtin_amdgcn_exp2f(sacc[jb][rg*4 + hv*2]);
          const float p1 = __builtin_amdgcn_exp2f(sacc[jb][rg*4 + hv*2 + 1]);
          lsum += p0 + p1;
          pk[jb][rg*2 + hv] =
              (unsigned)f2bf(p0) | ((unsigned)f2bf(p1) << 16);
        }

    // --- O^T += V^T @ P^T : P B-frags via permlane32_swap -----------------
    const char* Vp = (const char*)&Vb[cur][0];
    __builtin_amdgcn_s_setprio(1);
#pragma unroll
    for (int ks = 0; ks < 4; ++ks) {
      const int q2 = ks & 1, jb = ks >> 1;
      unsigned w0 = pk[jb][4*q2 + 0], w2v = pk[jb][4*q2 + 2];
      asm volatile("v_permlane32_swap_b32 %0, %1" : "+v"(w0), "+v"(w2v));
      unsigned w1 = pk[jb][4*q2 + 1], w3v = pk[jb][4*q2 + 3];
      asm volatile("v_permlane32_swap_b32 %0, %1" : "+v"(w1), "+v"(w3v));
      union { unsigned u[4]; bf16x8 v; } pb;
      pb.u[0] = w0; pb.u[1] = w1; pb.u[2] = w2v; pb.u[3] = w3v;
#pragma unroll
      for (int db = 0; db < 2; ++db) {
        const int row = db*32 + l32;
        const int slot = (ks*2 + hf) ^ (row & 7);
        bf16x8 vf = *(const bf16x8*)(Vp + row*128 + slot*16);
        oacc[db] = mfma32(vf, pb.v, oacc[db]);
      }
    }
    __builtin_amdgcn_s_setprio(0);

    asm volatile("" ::: "memory");
    __builtin_amdgcn_s_barrier();
  }

  // --- epilogue: UNNORMALIZED O + l; merge happens in combine_halves ------
  lsum += __shfl_xor(lsum, 32, 64);
  __hip_bfloat16* op = half ? ob : oa;
  const long base = ((long)qw*B + b)*512 + head*64;
#pragma unroll
  for (int db = 0; db < 2; ++db)
#pragma unroll
    for (int rq = 0; rq < 4; ++rq) {
      ushort4 pkk;
      pkk.x = f2bf(oacc[db][rq*4 + 0]);
      pkk.y = f2bf(oacc[db][rq*4 + 1]);
      pkk.z = f2bf(oacc[db][rq*4 + 2]);
      pkk.w = f2bf(oacc[db][rq*4 + 3]);
      *(ushort4*)(op + base + db*32 + rq*8 + hf*4) = pkk;
    }
  if (hf == 0)
    (half ? lb : la)[((long)qw*B + b)*8 + head] = lsum;
}

// ------------- combine: attn_g = (Oa + Ob) / (la + lb), in-place over Oa ---
__global__ __launch_bounds__(256) void combine_halves(
    const __hip_bfloat16* __restrict__ oa, const __hip_bfloat16* __restrict__ ob,
    const float* __restrict__ la, const float* __restrict__ lb,
    __hip_bfloat16* __restrict__ outg)
{
  const int i = blockIdx.x*256 + threadIdx.x;     // 2048 blocks x 8 elems
  const int row = i >> 6, c0 = (i & 63) << 3;
  const int h = c0 >> 6;
  const float inv = 1.f / (la[(long)row*8 + h] + lb[(long)row*8 + h]);
  u16x8 a = *(const u16x8*)(oa + (long)row*512 + c0);
  u16x8 bb = *(const u16x8*)(ob + (long)row*512 + c0);
  u16x8 r;
#pragma unroll
  for (int e = 0; e < 8; ++e)
    r[e] = f2bf((bf2f(a[e]) + bf2f(bb[e])) * inv);
  *(u16x8*)(outg + (long)row*512 + c0) = r;
}

// ------------- LOCAL flash: validated 16x16 kernel (nkt=2 per block) -------
__global__ __launch_bounds__(512) void flash_local(
    const __hip_bfloat16* __restrict__ qk, const __hip_bfloat16* __restrict__ vt,
    __hip_bfloat16* __restrict__ outb, const int* __restrict__ wptr,
    int S, int B)
{
  const int t = threadIdx.x, lane = t & 63, w = t >> 6;
  const int g16 = lane >> 4, l16 = lane & 15;
  const int id = blockIdx.x;
  const int Wn = wptr[0];
  const int xcd = id & 7, seq = id >> 3;
  const int bh = xcd + 8*(seq & 3);
  const int qt = seq >> 2;
  const int b = bh >> 3, h = bh & 7;
  const int q0 = qt * 128;
  const int kv0 = (q0 / Wn) * Wn;
  const int nkt = Wn >> 6;
  const int vtb = bh * 64;

  __shared__ __attribute__((aligned(16))) __hip_bfloat16 Kb[2][64*64];
  __shared__ __attribute__((aligned(16))) __hip_bfloat16 Vb[2][64*64];
  __shared__ __attribute__((aligned(16))) short Pl[8][16*72];

  const int qrow = q0 + w*16 + l16;
  bf16x8 qa[2];
  {
    const __hip_bfloat16* qp = qk + ((long)qrow*B + b)*1024 + h*64 + g16*8;
    qa[0] = *(const bf16x8*)(const void*)qp;
    qa[1] = *(const bf16x8*)(const void*)(qp + 32);
  }
  bf16x8 aones;
#pragma unroll
  for (int e = 0; e < 8; ++e) aones[e] = (short)0x3F80;

  f32x4 o[4] = {};
  f32x4 ol = {};

#define STAGE(tile, bufi)                                                      \
  {                                                                            \
    const int kvs_ = kv0 + (tile)*64;                                          \
    const int row_ = t >> 3;                                                   \
    const int sl_ = (t & 7) ^ (row_ & 7);                                      \
    gload_lds16(qk + ((long)(kvs_+row_)*B + b)*1024 + 512 + h*64 + sl_*8,      \
                (char*)&Kb[bufi][0] + t*16);                                   \
    gload_lds16(vt + (long)(vtb + row_)*2048 + kvs_ + sl_*8,                   \
                (char*)&Vb[bufi][0] + t*16);                                   \
  }

  STAGE(0, 0)

  for (int kt = 0; kt < nkt; ++kt) {
    const int cur = kt & 1;
    if (kt + 1 < nkt) {
      STAGE(kt + 1, cur ^ 1)
      asm volatile("s_waitcnt vmcnt(2)" ::: "memory");
    } else {
      asm volatile("s_waitcnt vmcnt(0)" ::: "memory");
    }
    __builtin_amdgcn_s_barrier();
    asm volatile("" ::: "memory");

    f32x4 s[4] = {};
    const char* Kp = (const char*)&Kb[cur][0];
    __builtin_amdgcn_s_setprio(1);
#pragma unroll
    for (int kk = 0; kk < 2; ++kk)
#pragma unroll
      for (int j = 0; j < 4; ++j) {
        const int row = j*16 + l16;
        const int slot = (kk*4 + g16) ^ (row & 7);
        bf16x8 kf = *(const bf16x8*)(Kp + row*128 + slot*16);
        s[j] = mfma16(kf, qa[kk], s[j]);
      }
    __builtin_amdgcn_s_setprio(0);

    short* Pw = &Pl[w][0];
#pragma unroll
    for (int j = 0; j < 4; ++j) {
      short4 pk4;
      pk4.x = (short)f2bf(__builtin_amdgcn_exp2f(s[j][0]));
      pk4.y = (short)f2bf(__builtin_amdgcn_exp2f(s[j][1]));
      pk4.z = (short)f2bf(__builtin_amdgcn_exp2f(s[j][2]));
      pk4.w = (short)f2bf(__builtin_amdgcn_exp2f(s[j][3]));
      *(short4*)(Pw + l16*72 + j*16 + g16*4) = pk4;
    }

    __builtin_amdgcn_s_setprio(1);
#pragma unroll
    for (int kk = 0; kk < 2; ++kk) {
      bf16x8 pf = *(const bf16x8*)(Pw + l16*72 + kk*32 + g16*8);
      ol = mfma16(aones, pf, ol);
#pragma unroll
      for (int dblk = 0; dblk < 4; ++dblk) {
        const int row = dblk*16 + l16;
        const int slot = (kk*4 + g16) ^ (row & 7);
        bf16x8 vf = *(const bf16x8*)((const char*)&Vb[cur][0] + row*128 + slot*16);
        o[dblk] = mfma16(vf, pf, o[dblk]);
      }
    }
    __builtin_amdgcn_s_setprio(0);

    asm volatile("" ::: "memory");
    __builtin_amdgcn_s_barrier();
  }

  const float inv = 1.f / ol[0];
  const long obase = ((long)qrow*B + b)*512 + h*64;
#pragma unroll
  for (int dblk = 0; dblk < 4; ++dblk) {
    ushort4 pk;
    pk.x = f2bf(o[dblk][0]*inv); pk.y = f2bf(o[dblk][1]*inv);
    pk.z = f2bf(o[dblk][2]*inv); pk.w = f2bf(o[dblk][3]*inv);
    *(ushort4*)(outb + obase + dblk*16 + g16*4) = pk;
  }
}

extern "C" void kernel_launch(void* const* d_in, const int* in_sizes, int n_in,
                              void* d_out, int out_size, void* d_ws, size_t ws_size,
                              hipStream_t stream) {
  const float* x   = (const float*)d_in[0];
  const float* wig = (const float*)d_in[1];
  const float* big = (const float*)d_in[2];
  const float* wog = (const float*)d_in[3];
  const float* bog = (const float*)d_in[4];
  const float* wil = (const float*)d_in[5];
  const float* bil = (const float*)d_in[6];
  const float* wol = (const float*)d_in[7];
  const float* bol = (const float*)d_in[8];
  const int*   wsz = (const int*)d_in[9];

  char* ws = (char*)d_ws;
  __hip_bfloat16* xb    = (__hip_bfloat16*)(ws + 0);          // 8 MB
  __hip_bfloat16* wigb  = (__hip_bfloat16*)(ws + 8388608);
  __hip_bfloat16* wilb  = (__hip_bfloat16*)(ws + 9961472);
  __hip_bfloat16* wogb  = (__hip_bfloat16*)(ws + 11534336);
  __hip_bfloat16* wolb  = (__hip_bfloat16*)(ws + 12058624);
  __hip_bfloat16* qkg   = (__hip_bfloat16*)(ws + 12582912);   // 16 MB
  __hip_bfloat16* qkl   = (__hip_bfloat16*)(ws + 29360128);   // 16 MB
  __hip_bfloat16* vtg   = (__hip_bfloat16*)(ws + 46137344);   // 8 MB
  __hip_bfloat16* vtl   = (__hip_bfloat16*)(ws + 54525952);   // 8 MB (end 60)

  // Split-kv scratch (R15-validated plan): Oa -> xb (dead after qkv; becomes
  // attn_g in-place), Ob -> d_out (dead until gemm_out), la/lb -> wigb zone
  // (dead after qkv).
  __hip_bfloat16* oa    = xb;
  __hip_bfloat16* ob    = (__hip_bfloat16*)d_out;
  float*          la    = (float*)(ws + 8388608);
  float*          lb    = (float*)(ws + 8650752);
  __hip_bfloat16* attng = xb;

  const int big_ws = ws_size >= (size_t)71303168;              // 68 MB
  __hip_bfloat16* attnl = big_ws ? (__hip_bfloat16*)(ws + 62914560)
                                 : qkg;   // safe: local runs after g256 (qkg dead)

  convert_all<<<6144, 256, 0, stream>>>(
      (const float4*)x, (const float4*)wig, (const float4*)wil,
      (const float4*)wog, (const float4*)wol, (ushort4*)ws);

  gemm_qkv<<<1536, 512, 0, stream>>>(xb, wigb, big, wilb, bil,
                                     qkg, vtg, qkl, vtl, 8192, 1536, 512);

  flash_g256<<<512, 512, 0, stream>>>(qkg, vtg, oa, ob, la, lb, 2048, 4);
  flash_local<<<512, 512, 0, stream>>>(qkl, vtl, attnl, wsz, 2048, 4);
  combine_halves<<<2048, 256, 0, stream>>>(oa, ob, la, lb, attng);

  gemm_out<<<512, 512, 0, stream>>>(attng, wogb, bog, attnl, wolb, bol,
                                    (float*)d_out, 8192, 512, 512);
}

// Round 21
// 111.384 us; speedup vs baseline: 1.1438x; 1.1307x over previous
//
#include <hip/hip_runtime.h>
#include <hip/hip_bf16.h>
#include <stdint.h>

typedef __attribute__((ext_vector_type(8))) short bf16x8;
typedef __attribute__((ext_vector_type(8))) unsigned short u16x8;
typedef __attribute__((ext_vector_type(4))) float f32x4;

#define DEV __device__ __forceinline__

DEV f32x4 mfma16(bf16x8 a, bf16x8 b, f32x4 c) {
  return __builtin_amdgcn_mfma_f32_16x16x32_bf16(a, b, c, 0, 0, 0);
}

DEV void gload_lds16(const void* g, void* l) {
  __builtin_amdgcn_global_load_lds(
      (__attribute__((address_space(1))) void*)(g),
      (__attribute__((address_space(3))) void*)(l), 16, 0, 0);
}

DEV unsigned short f2bf(float f) {
  __hip_bfloat16 h = __float2bfloat16(f);
  return __builtin_bit_cast(unsigned short, h);
}

// ------------- convert fp32 -> bf16: x + 4 weight mats into contiguous ws ---
__global__ __launch_bounds__(256) void convert_all(
    const float4* __restrict__ s0, const float4* __restrict__ s1,
    const float4* __restrict__ s2, const float4* __restrict__ s3,
    const float4* __restrict__ s4, ushort4* __restrict__ dst)
{
  const int n0 = 1048576, n1 = 196608, n3 = 65536;
  int i = blockIdx.x * 256 + threadIdx.x;
  const float4* s; int off;
  if (i < n0)                 { s = s0; off = 0; }
  else if (i < n0 + n1)       { s = s1; off = n0; }
  else if (i < n0 + 2*n1)     { s = s2; off = n0 + n1; }
  else if (i < n0 + 2*n1+n3)  { s = s3; off = n0 + 2*n1; }
  else                        { s = s4; off = n0 + 2*n1 + n3; }
  float4 v = s[i - off];
  ushort4 o;
  o.x = f2bf(v.x); o.y = f2bf(v.y); o.z = f2bf(v.z); o.w = f2bf(v.w);
  dst[i] = o;
}

// ---- 512-thread 2-phase GEMM skeleton --------------------------------------
#define GEMM_STAGE(Ap, Wp, k0v, bufi)                                          \
  {                                                                            \
    _Pragma("unroll")                                                          \
    for (int is = 0; is < 2; ++is) {                                           \
      const int row = is*64 + (t >> 3);                                        \
      const int slot = (t & 7) ^ (row & 7);                                    \
      gload_lds16((Ap) + (long)(m0 + row)*K + (k0v) + slot*8,                  \
                  (char*)&As[bufi][0] + (is*512 + t)*16);                      \
      gload_lds16((Wp) + (long)(n0 + row)*K + (k0v) + slot*8,                  \
                  (char*)&Ws[bufi][0] + (is*512 + t)*16);                      \
    }                                                                          \
  }

#define GEMM_COMPUTE(cur, NJ, WCMUL)                                           \
  {                                                                            \
    const char* Apl = (const char*)&As[cur][0];                                \
    const char* Wpl = (const char*)&Ws[cur][0];                                \
    __builtin_amdgcn_s_setprio(1);                                             \
    _Pragma("unroll")                                                          \
    for (int kk = 0; kk < 2; ++kk) {                                           \
      bf16x8 af[4], wf[NJ];                                                    \
      _Pragma("unroll")                                                        \
      for (int i = 0; i < 4; ++i) {                                            \
        const int row = wr*64 + i*16 + l16;                                    \
        const int slot = (kk*4 + g16) ^ (row & 7);                             \
        af[i] = *(const bf16x8*)(Apl + row*128 + slot*16);                     \
      }                                                                        \
      _Pragma("unroll")                                                        \
      for (int j = 0; j < NJ; ++j) {                                           \
        const int row = wc*WCMUL + j*16 + l16;                                 \
        const int slot = (kk*4 + g16) ^ (row & 7);                             \
        wf[j] = *(const bf16x8*)(Wpl + row*128 + slot*16);                     \
      }                                                                        \
      _Pragma("unroll")                                                        \
      for (int i = 0; i < 4; ++i)                                              \
        _Pragma("unroll")                                                      \
        for (int j = 0; j < NJ; ++j)                                           \
          acc[i][j] = mfma16(af[i], wf[j], acc[i][j]);                         \
    }                                                                          \
    __builtin_amdgcn_s_setprio(0);                                             \
  }

// ------------- merged QKV GEMM: XCD-partitioned (0-3 global, 4-7 local) ----
// Q (gc<512)        -> qk[m][gc]                (row-major, ld 1024)
// K (512<=gc<1024)  -> qk[m][gc] * c2           (softmax scale folded in)
// V (gc>=1024)      -> vt[(m&3)*512 + gc-1024][m>>2] via LDS transpose.
__global__ __launch_bounds__(512) void gemm_qkv(
    const __hip_bfloat16* __restrict__ A0,
    const __hip_bfloat16* __restrict__ Wg, const float* __restrict__ bg,
    const __hip_bfloat16* __restrict__ Wl, const float* __restrict__ bl,
    __hip_bfloat16* __restrict__ qkg, __hip_bfloat16* __restrict__ vtg,
    __hip_bfloat16* __restrict__ qkl, __hip_bfloat16* __restrict__ vtl,
    int M, int N, int K)
{
  __shared__ __attribute__((aligned(16))) char SMEM[65536];
  __hip_bfloat16 (*As)[8192] = (__hip_bfloat16(*)[8192])SMEM;
  __hip_bfloat16 (*Ws)[8192] = (__hip_bfloat16(*)[8192])(SMEM + 32768);
  const int t = threadIdx.x;
  const int lane = t & 63, wid = t >> 6;
  const int g16 = lane >> 4, l16 = lane & 15;
  const int wr = wid >> 2, wc = wid & 3;
  const int bid = blockIdx.x;
  const int xcd = bid & 7, seq = bid >> 3;          // seq 0..191
  const int sel = xcd >= 4;                          // 0=global, 1=local
  const int xh = xcd & 3;
  const int m0 = (xh*16 + (seq & 15)) * 128;
  const int n0 = (seq >> 4) * 128;
  const __hip_bfloat16* W0 = sel ? Wl : Wg;
  const float* b0 = sel ? bl : bg;
  __hip_bfloat16* qkp = sel ? qkl : qkg;
  __hip_bfloat16* vtp = sel ? vtl : vtg;

  f32x4 acc[4][2] = {};
  const int nks = K >> 6;          // 8

  GEMM_STAGE(A0, W0, 0, 0)
  for (int step = 0; step < nks; ++step) {
    const int cur = step & 1;
    if (step + 1 < nks) {
      GEMM_STAGE(A0, W0, (step+1) << 6, cur ^ 1)
      asm volatile("s_waitcnt vmcnt(4)" ::: "memory");
    } else {
      asm volatile("s_waitcnt vmcnt(0)" ::: "memory");
    }
    __builtin_amdgcn_s_barrier();
    asm volatile("" ::: "memory");
    GEMM_COMPUTE(cur, 2, 32)
    asm volatile("" ::: "memory");
    __builtin_amdgcn_s_barrier();
  }

  if (n0 < 1024) {
#pragma unroll
    for (int i = 0; i < 4; ++i) {
      const int gr = m0 + wr*64 + i*16 + g16*4;
#pragma unroll
      for (int j = 0; j < 2; ++j) {
        const int gc = n0 + wc*32 + j*16 + l16;
        const float bias = b0[gc];
        const float scl = (gc >= 512) ? 0.180336880f : 1.0f;  // 0.125*log2(e)
#pragma unroll
        for (int r = 0; r < 4; ++r)
          qkp[(long)(gr + r)*1024 + gc] =
              __float2bfloat16((acc[i][j][r] + bias) * scl);
      }
    }
  } else {
    const int n0l = n0 - 1024;
    short* T = (short*)SMEM;
#pragma unroll
    for (int i = 0; i < 4; ++i) {
      const int sl = wr*16 + i*4 + g16;
#pragma unroll
      for (int j = 0; j < 2; ++j) {
        const int gcl = wc*32 + j*16 + l16;
        const float bias = b0[n0 + gcl];
#pragma unroll
        for (int r = 0; r < 4; ++r)
          T[gcl*136 + r*32 + sl] = (short)f2bf(acc[i][j][r] + bias);
      }
    }
    __syncthreads();
    const int d = t & 127, b4 = t >> 7;
    __hip_bfloat16* dst = vtp + ((long)(b4*512 + n0l + d))*2048 + (m0 >> 2);
#pragma unroll
    for (int k = 0; k < 4; ++k) {
      u16x8 v = *(const u16x8*)(T + d*136 + b4*32 + k*8);
      *(u16x8*)(dst + k*8) = v;
    }
  }
}

// ------------- final GEMM: 128x64 tile, 512 blocks (2/CU) ------------------
__global__ __launch_bounds__(512) void gemm_out(
    const __hip_bfloat16* __restrict__ A0, const __hip_bfloat16* __restrict__ W0,
    const float* __restrict__ b0,
    const __hip_bfloat16* __restrict__ A1, const __hip_bfloat16* __restrict__ W1,
    const float* __restrict__ b1,
    float* __restrict__ Cout, int M, int N, int K)
{
  __shared__ __attribute__((aligned(16))) __hip_bfloat16 As[2][128*64];
  __shared__ __attribute__((aligned(16))) __hip_bfloat16 Ws[2][64*64];
  const int t = threadIdx.x;
  const int lane = t & 63, wid = t >> 6;
  const int g16 = lane >> 4, l16 = lane & 15;
  const int wr = wid >> 2, wc = wid & 3;
  const int bid = blockIdx.x;                       // grid 512
  const int xcd = bid & 7, pos = bid >> 3;          // pos 0..63
  const int m0 = (xcd*8 + (pos & 7)) * 128, n0 = (pos >> 3) * 64;

  f32x4 acc[4][1] = {};
  const int nks = K >> 6;
  const int NS = 2*nks;

#define OUT_STAGE(Ap, Wp, k0v, bufi)                                           \
  {                                                                            \
    _Pragma("unroll")                                                          \
    for (int is = 0; is < 2; ++is) {                                           \
      const int row = is*64 + (t >> 3);                                        \
      const int slot = (t & 7) ^ (row & 7);                                    \
      gload_lds16((Ap) + (long)(m0 + row)*K + (k0v) + slot*8,                  \
                  (char*)&As[bufi][0] + (is*512 + t)*16);                      \
    }                                                                          \
    {                                                                          \
      const int row = t >> 3;                                                  \
      const int slot = (t & 7) ^ (row & 7);                                    \
      gload_lds16((Wp) + (long)(n0 + row)*K + (k0v) + slot*8,                  \
                  (char*)&Ws[bufi][0] + t*16);                                 \
    }                                                                          \
  }

  OUT_STAGE(A0, W0, 0, 0)
  for (int step = 0; step < NS; ++step) {
    const int cur = step & 1;
    if (step + 1 < NS) {
      const int nstep = step + 1;
      const __hip_bfloat16* Ap = (nstep >= nks) ? A1 : A0;
      const __hip_bfloat16* Wp = (nstep >= nks) ? W1 : W0;
      const int k0 = ((nstep >= nks) ? (nstep - nks) : nstep) << 6;
      OUT_STAGE(Ap, Wp, k0, cur ^ 1)
      asm volatile("s_waitcnt vmcnt(3)" ::: "memory");
    } else {
      asm volatile("s_waitcnt vmcnt(0)" ::: "memory");
    }
    __builtin_amdgcn_s_barrier();
    asm volatile("" ::: "memory");
    GEMM_COMPUTE(cur, 1, 16)
    asm volatile("" ::: "memory");
    __builtin_amdgcn_s_barrier();
  }

#pragma unroll
  for (int i = 0; i < 4; ++i) {
    const int gr = m0 + wr*64 + i*16 + g16*4;
    const int gc = n0 + wc*16 + l16;
    const float bias = b0[gc] + b1[gc];
#pragma unroll
    for (int r = 0; r < 4; ++r)
      Cout[(long)(gr + r)*N + gc] = acc[i][0][r] + bias;
  }
}

// ------------- flash attention: merged global+local, 128 q, 8 waves --------
// qk: [(s*B+b)*1024 + {0:Q, 512:K*c2} + h*64 + d]; vt: [b*512+h*64+d][s].
// S^T = mfma(K, Q): lane (g16,l16) owns q-row l16, kv = 16j + 4*g16 + r.
// RAW softmax in exp2 domain; scale pre-folded into K -> p = exp2(s) direct.
// l via ones-A MFMA. P roundtrips per-wave LDS (k32 layout, 54.5us-validated).
__global__ __launch_bounds__(512) void flash_all(
    const __hip_bfloat16* __restrict__ qkg, const __hip_bfloat16* __restrict__ vtg,
    __hip_bfloat16* __restrict__ outg,
    const __hip_bfloat16* __restrict__ qkl, const __hip_bfloat16* __restrict__ vtl,
    __hip_bfloat16* __restrict__ outl,
    const int* __restrict__ wptr, int S, int B, int blkoff)
{
  const int t = threadIdx.x, lane = t & 63, w = t >> 6;
  const int g16 = lane >> 4, l16 = lane & 15;
  const int gid = blockIdx.x + blkoff;
  const int isl = gid >= 512;
  const int id = gid & 511;
  const __hip_bfloat16* qk = isl ? qkl : qkg;
  const __hip_bfloat16* vt = isl ? vtl : vtg;
  __hip_bfloat16* outb = isl ? outl : outg;
  const int Wn = isl ? wptr[0] : S;
  const int xcd = id & 7, seq = id >> 3;
  const int bh = xcd + 8*(seq & 3);
  const int qt = seq >> 2;
  const int b = bh >> 3, h = bh & 7;
  const int q0 = qt * 128;
  const int kv0 = (q0 / Wn) * Wn;
  const int nkt = Wn >> 6;
  const int vtb = bh * 64;               // = b*512 + h*64

  __shared__ __attribute__((aligned(16))) __hip_bfloat16 Kb[2][64*64];
  __shared__ __attribute__((aligned(16))) __hip_bfloat16 Vb[2][64*64];
  __shared__ __attribute__((aligned(16))) short Pl[8][16*72];

  const int qrow = q0 + w*16 + l16;
  bf16x8 qa[2];
  {
    const __hip_bfloat16* qp = qk + ((long)qrow*B + b)*1024 + h*64 + g16*8;
    qa[0] = *(const bf16x8*)(const void*)qp;
    qa[1] = *(const bf16x8*)(const void*)(qp + 32);
  }
  bf16x8 aones;
#pragma unroll
  for (int e = 0; e < 8; ++e) aones[e] = (short)0x3F80;   // bf16 1.0

  f32x4 o[4] = {};
  f32x4 ol = {};

#define STAGE(tile, bufi)                                                      \
  {                                                                            \
    const int kvs_ = kv0 + (tile)*64;                                          \
    const int row_ = t >> 3;                                                   \
    const int sl_ = (t & 7) ^ (row_ & 7);                                      \
    gload_lds16(qk + ((long)(kvs_+row_)*B + b)*1024 + 512 + h*64 + sl_*8,      \
                (char*)&Kb[bufi][0] + t*16);                                   \
    gload_lds16(vt + (long)(vtb + row_)*2048 + kvs_ + sl_*8,                   \
                (char*)&Vb[bufi][0] + t*16);                                   \
  }

  STAGE(0, 0)

  for (int kt = 0; kt < nkt; ++kt) {
    const int cur = kt & 1;
    if (kt + 1 < nkt) {
      STAGE(kt + 1, cur ^ 1)
      asm volatile("s_waitcnt vmcnt(2)" ::: "memory");
    } else {
      asm volatile("s_waitcnt vmcnt(0)" ::: "memory");
    }
    __builtin_amdgcn_s_barrier();
    asm volatile("" ::: "memory");

    f32x4 s[4] = {};
    const char* Kp = (const char*)&Kb[cur][0];
    __builtin_amdgcn_s_setprio(1);
#pragma unroll
    for (int kk = 0; kk < 2; ++kk)
#pragma unroll
      for (int j = 0; j < 4; ++j) {
        const int row = j*16 + l16;
        const int slot = (kk*4 + g16) ^ (row & 7);
        bf16x8 kf = *(const bf16x8*)(Kp + row*128 + slot*16);
        s[j] = mfma16(kf, qa[kk], s[j]);
      }
    __builtin_amdgcn_s_setprio(0);

    short* Pw = &Pl[w][0];
#pragma unroll
    for (int j = 0; j < 4; ++j) {
      short4 pk4;
      pk4.x = (short)f2bf(__builtin_amdgcn_exp2f(s[j][0]));
      pk4.y = (short)f2bf(__builtin_amdgcn_exp2f(s[j][1]));
      pk4.z = (short)f2bf(__builtin_amdgcn_exp2f(s[j][2]));
      pk4.w = (short)f2bf(__builtin_amdgcn_exp2f(s[j][3]));
      *(short4*)(Pw + l16*72 + j*16 + g16*4) = pk4;
    }

    __builtin_amdgcn_s_setprio(1);
#pragma unroll
    for (int kk = 0; kk < 2; ++kk) {
      bf16x8 pf = *(const bf16x8*)(Pw + l16*72 + kk*32 + g16*8);
      ol = mfma16(aones, pf, ol);
#pragma unroll
      for (int dblk = 0; dblk < 4; ++dblk) {
        const int row = dblk*16 + l16;
        const int slot = (kk*4 + g16) ^ (row & 7);
        bf16x8 vf = *(const bf16x8*)((const char*)&Vb[cur][0] + row*128 + slot*16);
        o[dblk] = mfma16(vf, pf, o[dblk]);
      }
    }
    __builtin_amdgcn_s_setprio(0);

    asm volatile("" ::: "memory");
    __builtin_amdgcn_s_barrier();
  }

  const float inv = 1.f / ol[0];
  const long obase = ((long)qrow*B + b)*512 + h*64;
#pragma unroll
  for (int dblk = 0; dblk < 4; ++dblk) {
    ushort4 pk;
    pk.x = f2bf(o[dblk][0]*inv); pk.y = f2bf(o[dblk][1]*inv);
    pk.z = f2bf(o[dblk][2]*inv); pk.w = f2bf(o[dblk][3]*inv);
    *(ushort4*)(outb + obase + dblk*16 + g16*4) = pk;
  }
}

extern "C" void kernel_launch(void* const* d_in, const int* in_sizes, int n_in,
                              void* d_out, int out_size, void* d_ws, size_t ws_size,
                              hipStream_t stream) {
  const float* x   = (const float*)d_in[0];
  const float* wig = (const float*)d_in[1];
  const float* big = (const float*)d_in[2];
  const float* wog = (const float*)d_in[3];
  const float* bog = (const float*)d_in[4];
  const float* wil = (const float*)d_in[5];
  const float* bil = (const float*)d_in[6];
  const float* wol = (const float*)d_in[7];
  const float* bol = (const float*)d_in[8];
  const int*   wsz = (const int*)d_in[9];

  char* ws = (char*)d_ws;
  __hip_bfloat16* xb    = (__hip_bfloat16*)(ws + 0);          // 8 MB (-> attn_g)
  __hip_bfloat16* wigb  = (__hip_bfloat16*)(ws + 8388608);
  __hip_bfloat16* wilb  = (__hip_bfloat16*)(ws + 9961472);
  __hip_bfloat16* wogb  = (__hip_bfloat16*)(ws + 11534336);
  __hip_bfloat16* wolb  = (__hip_bfloat16*)(ws + 12058624);
  __hip_bfloat16* qkg   = (__hip_bfloat16*)(ws + 12582912);   // 16 MB
  __hip_bfloat16* qkl   = (__hip_bfloat16*)(ws + 29360128);   // 16 MB
  __hip_bfloat16* vtg   = (__hip_bfloat16*)(ws + 46137344);   // 8 MB
  __hip_bfloat16* vtl   = (__hip_bfloat16*)(ws + 54525952);   // 8 MB (end 60 MB)
  __hip_bfloat16* attng = xb;                                  // xb dead after qkv

  const int big_ws = ws_size >= (size_t)71303168;              // 68 MB
  __hip_bfloat16* attnl = big_ws ? (__hip_bfloat16*)(ws + 62914560)
                                 : qkg;                        // fallback alias

  convert_all<<<6144, 256, 0, stream>>>(
      (const float4*)x, (const float4*)wig, (const float4*)wil,
      (const float4*)wog, (const float4*)wol, (ushort4*)ws);

  gemm_qkv<<<1536, 512, 0, stream>>>(xb, wigb, big, wilb, bil,
                                     qkg, vtg, qkl, vtl, 8192, 1536, 512);

  if (big_ws) {
    flash_all<<<1024, 512, 0, stream>>>(qkg, vtg, attng, qkl, vtl, attnl,
                                        wsz, 2048, 4, 0);
  } else {
    flash_all<<<512, 512, 0, stream>>>(qkg, vtg, attng, qkl, vtl, attnl,
                                       wsz, 2048, 4, 0);
    flash_all<<<512, 512, 0, stream>>>(qkg, vtg, attng, qkl, vtl, attnl,
                                       wsz, 2048, 4, 512);
  }

  gemm_out<<<512, 512, 0, stream>>>(attng, wogb, bog, attnl, wolb, bol,
                                    (float*)d_out, 8192, 512, 512);
}

// Round 22
// 111.342 us; speedup vs baseline: 1.1443x; 1.0004x over previous
//
#include <hip/hip_runtime.h>
#include <hip/hip_bf16.h>
#include <stdint.h>

typedef __attribute__((ext_vector_type(8))) short bf16x8;
typedef __attribute__((ext_vector_type(8))) unsigned short u16x8;
typedef __attribute__((ext_vector_type(4))) float f32x4;

#define DEV __device__ __forceinline__

DEV f32x4 mfma16(bf16x8 a, bf16x8 b, f32x4 c) {
  return __builtin_amdgcn_mfma_f32_16x16x32_bf16(a, b, c, 0, 0, 0);
}

DEV void gload_lds16(const void* g, void* l) {
  __builtin_amdgcn_global_load_lds(
      (__attribute__((address_space(1))) void*)(g),
      (__attribute__((address_space(3))) void*)(l), 16, 0, 0);
}

DEV unsigned short f2bf(float f) {
  __hip_bfloat16 h = __float2bfloat16(f);
  return __builtin_bit_cast(unsigned short, h);
}

// ------------- convert fp32 -> bf16: x + 4 weight mats into contiguous ws ---
__global__ __launch_bounds__(256) void convert_all(
    const float4* __restrict__ s0, const float4* __restrict__ s1,
    const float4* __restrict__ s2, const float4* __restrict__ s3,
    const float4* __restrict__ s4, ushort4* __restrict__ dst)
{
  const int n0 = 1048576, n1 = 196608, n3 = 65536;
  int i = blockIdx.x * 256 + threadIdx.x;
  const float4* s; int off;
  if (i < n0)                 { s = s0; off = 0; }
  else if (i < n0 + n1)       { s = s1; off = n0; }
  else if (i < n0 + 2*n1)     { s = s2; off = n0 + n1; }
  else if (i < n0 + 2*n1+n3)  { s = s3; off = n0 + 2*n1; }
  else                        { s = s4; off = n0 + 2*n1 + n3; }
  float4 v = s[i - off];
  ushort4 o;
  o.x = f2bf(v.x); o.y = f2bf(v.y); o.z = f2bf(v.z); o.w = f2bf(v.w);
  dst[i] = o;
}

// ---- 512-thread 2-phase GEMM skeleton --------------------------------------
#define GEMM_STAGE(Ap, Wp, k0v, bufi)                                          \
  {                                                                            \
    _Pragma("unroll")                                                          \
    for (int is = 0; is < 2; ++is) {                                           \
      const int row = is*64 + (t >> 3);                                        \
      const int slot = (t & 7) ^ (row & 7);                                    \
      gload_lds16((Ap) + (long)(m0 + row)*K + (k0v) + slot*8,                  \
                  (char*)&As[bufi][0] + (is*512 + t)*16);                      \
      gload_lds16((Wp) + (long)(n0 + row)*K + (k0v) + slot*8,                  \
                  (char*)&Ws[bufi][0] + (is*512 + t)*16);                      \
    }                                                                          \
  }

#define GEMM_COMPUTE(cur, NJ, WCMUL)                                           \
  {                                                                            \
    const char* Apl = (const char*)&As[cur][0];                                \
    const char* Wpl = (const char*)&Ws[cur][0];                                \
    __builtin_amdgcn_s_setprio(1);                                             \
    _Pragma("unroll")                                                          \
    for (int kk = 0; kk < 2; ++kk) {                                           \
      bf16x8 af[4], wf[NJ];                                                    \
      _Pragma("unroll")                                                        \
      for (int i = 0; i < 4; ++i) {                                            \
        const int row = wr*64 + i*16 + l16;                                    \
        const int slot = (kk*4 + g16) ^ (row & 7);                             \
        af[i] = *(const bf16x8*)(Apl + row*128 + slot*16);                     \
      }                                                                        \
      _Pragma("unroll")                                                        \
      for (int j = 0; j < NJ; ++j) {                                           \
        const int row = wc*WCMUL + j*16 + l16;                                 \
        const int slot = (kk*4 + g16) ^ (row & 7);                             \
        wf[j] = *(const bf16x8*)(Wpl + row*128 + slot*16);                     \
      }                                                                        \
      _Pragma("unroll")                                                        \
      for (int i = 0; i < 4; ++i)                                              \
        _Pragma("unroll")                                                      \
        for (int j = 0; j < NJ; ++j)                                           \
          acc[i][j] = mfma16(af[i], wf[j], acc[i][j]);                         \
    }                                                                          \
    __builtin_amdgcn_s_setprio(0);                                             \
  }

// ------------- merged QKV GEMM: XCD-partitioned (0-3 global, 4-7 local) ----
// Q (gc<512)        -> qk[m][gc]                (row-major, ld 1024)
// K (512<=gc<1024)  -> qk[m][gc] * c2           (softmax scale folded in)
// V (gc>=1024)      -> vt[(m&3)*512 + gc-1024][m>>2] via LDS transpose.
__global__ __launch_bounds__(512) void gemm_qkv(
    const __hip_bfloat16* __restrict__ A0,
    const __hip_bfloat16* __restrict__ Wg, const float* __restrict__ bg,
    const __hip_bfloat16* __restrict__ Wl, const float* __restrict__ bl,
    __hip_bfloat16* __restrict__ qkg, __hip_bfloat16* __restrict__ vtg,
    __hip_bfloat16* __restrict__ qkl, __hip_bfloat16* __restrict__ vtl,
    int M, int N, int K)
{
  __shared__ __attribute__((aligned(16))) char SMEM[65536];
  __hip_bfloat16 (*As)[8192] = (__hip_bfloat16(*)[8192])SMEM;
  __hip_bfloat16 (*Ws)[8192] = (__hip_bfloat16(*)[8192])(SMEM + 32768);
  const int t = threadIdx.x;
  const int lane = t & 63, wid = t >> 6;
  const int g16 = lane >> 4, l16 = lane & 15;
  const int wr = wid >> 2, wc = wid & 3;
  const int bid = blockIdx.x;
  const int xcd = bid & 7, seq = bid >> 3;          // seq 0..191
  const int sel = xcd >= 4;                          // 0=global, 1=local
  const int xh = xcd & 3;
  const int m0 = (xh*16 + (seq & 15)) * 128;
  const int n0 = (seq >> 4) * 128;
  const __hip_bfloat16* W0 = sel ? Wl : Wg;
  const float* b0 = sel ? bl : bg;
  __hip_bfloat16* qkp = sel ? qkl : qkg;
  __hip_bfloat16* vtp = sel ? vtl : vtg;

  f32x4 acc[4][2] = {};
  const int nks = K >> 6;          // 8

  GEMM_STAGE(A0, W0, 0, 0)
  for (int step = 0; step < nks; ++step) {
    const int cur = step & 1;
    if (step + 1 < nks) {
      GEMM_STAGE(A0, W0, (step+1) << 6, cur ^ 1)
      asm volatile("s_waitcnt vmcnt(4)" ::: "memory");
    } else {
      asm volatile("s_waitcnt vmcnt(0)" ::: "memory");
    }
    __builtin_amdgcn_s_barrier();
    asm volatile("" ::: "memory");
    GEMM_COMPUTE(cur, 2, 32)
    asm volatile("" ::: "memory");
    __builtin_amdgcn_s_barrier();
  }

  if (n0 < 1024) {
#pragma unroll
    for (int i = 0; i < 4; ++i) {
      const int gr = m0 + wr*64 + i*16 + g16*4;
#pragma unroll
      for (int j = 0; j < 2; ++j) {
        const int gc = n0 + wc*32 + j*16 + l16;
        const float bias = b0[gc];
        const float scl = (gc >= 512) ? 0.180336880f : 1.0f;  // 0.125*log2(e)
#pragma unroll
        for (int r = 0; r < 4; ++r)
          qkp[(long)(gr + r)*1024 + gc] =
              __float2bfloat16((acc[i][j][r] + bias) * scl);
      }
    }
  } else {
    const int n0l = n0 - 1024;
    short* T = (short*)SMEM;
#pragma unroll
    for (int i = 0; i < 4; ++i) {
      const int sl = wr*16 + i*4 + g16;
#pragma unroll
      for (int j = 0; j < 2; ++j) {
        const int gcl = wc*32 + j*16 + l16;
        const float bias = b0[n0 + gcl];
#pragma unroll
        for (int r = 0; r < 4; ++r)
          T[gcl*136 + r*32 + sl] = (short)f2bf(acc[i][j][r] + bias);
      }
    }
    __syncthreads();
    const int d = t & 127, b4 = t >> 7;
    __hip_bfloat16* dst = vtp + ((long)(b4*512 + n0l + d))*2048 + (m0 >> 2);
#pragma unroll
    for (int k = 0; k < 4; ++k) {
      u16x8 v = *(const u16x8*)(T + d*136 + b4*32 + k*8);
      *(u16x8*)(dst + k*8) = v;
    }
  }
}

// ------------- final GEMM: 64x64 tile, grid 1024 (4 blocks/CU) -------------
// out = attn_g @ wog^T + bog + attn_l @ wol^T + bol  (fp32 out). The kernel
// is latency-bound; smaller tiles double the co-resident block pool (R18's
// retile mechanism, extended). 8 waves: wr = wid&3 (m-tile), wc = wid>>2.
__global__ __launch_bounds__(512) void gemm_out(
    const __hip_bfloat16* __restrict__ A0, const __hip_bfloat16* __restrict__ W0,
    const float* __restrict__ b0,
    const __hip_bfloat16* __restrict__ A1, const __hip_bfloat16* __restrict__ W1,
    const float* __restrict__ b1,
    float* __restrict__ Cout, int M, int N, int K)
{
  __shared__ __attribute__((aligned(16))) __hip_bfloat16 As[2][64*64];
  __shared__ __attribute__((aligned(16))) __hip_bfloat16 Ws[2][64*64];
  const int t = threadIdx.x;
  const int lane = t & 63, wid = t >> 6;
  const int g16 = lane >> 4, l16 = lane & 15;
  const int wr = wid & 3, wc = wid >> 2;
  const int bid = blockIdx.x;                       // grid 1024
  const int xcd = bid & 7, pos = bid >> 3;          // pos 0..127
  const int m0 = (xcd*16 + (pos & 15)) * 64;        // 128 m-tiles
  const int n0 = (pos >> 4) * 64;                   // 8 n-tiles

  f32x4 acc[2] = {};
  const int nks = K >> 6;
  const int NS = 2*nks;

#define OUT_STAGE(Ap, Wp, k0v, bufi)                                           \
  {                                                                            \
    const int row = t >> 3;                                                    \
    const int slot = (t & 7) ^ (row & 7);                                      \
    gload_lds16((Ap) + (long)(m0 + row)*K + (k0v) + slot*8,                    \
                (char*)&As[bufi][0] + t*16);                                   \
    gload_lds16((Wp) + (long)(n0 + row)*K + (k0v) + slot*8,                    \
                (char*)&Ws[bufi][0] + t*16);                                   \
  }

  OUT_STAGE(A0, W0, 0, 0)
  for (int step = 0; step < NS; ++step) {
    const int cur = step & 1;
    if (step + 1 < NS) {
      const int nstep = step + 1;
      const __hip_bfloat16* Ap = (nstep >= nks) ? A1 : A0;
      const __hip_bfloat16* Wp = (nstep >= nks) ? W1 : W0;
      const int k0 = ((nstep >= nks) ? (nstep - nks) : nstep) << 6;
      OUT_STAGE(Ap, Wp, k0, cur ^ 1)
      asm volatile("s_waitcnt vmcnt(2)" ::: "memory");
    } else {
      asm volatile("s_waitcnt vmcnt(0)" ::: "memory");
    }
    __builtin_amdgcn_s_barrier();
    asm volatile("" ::: "memory");
    {
      const char* Apl = (const char*)&As[cur][0];
      const char* Wpl = (const char*)&Ws[cur][0];
      __builtin_amdgcn_s_setprio(1);
#pragma unroll
      for (int kk = 0; kk < 2; ++kk) {
        const int arow = wr*16 + l16;
        const int aslot = (kk*4 + g16) ^ (arow & 7);
        bf16x8 af = *(const bf16x8*)(Apl + arow*128 + aslot*16);
#pragma unroll
        for (int j = 0; j < 2; ++j) {
          const int row = wc*32 + j*16 + l16;
          const int slot = (kk*4 + g16) ^ (row & 7);
          bf16x8 wf = *(const bf16x8*)(Wpl + row*128 + slot*16);
          acc[j] = mfma16(af, wf, acc[j]);
        }
      }
      __builtin_amdgcn_s_setprio(0);
    }
    asm volatile("" ::: "memory");
    __builtin_amdgcn_s_barrier();
  }

#pragma unroll
  for (int j = 0; j < 2; ++j) {
    const int gr = m0 + wr*16 + g16*4;
    const int gc = n0 + wc*32 + j*16 + l16;
    const float bias = b0[gc] + b1[gc];
#pragma unroll
    for (int r = 0; r < 4; ++r)
      Cout[(long)(gr + r)*N + gc] = acc[j][r] + bias;
  }
}

// ------------- flash attention: merged global+local, 128 q, 8 waves --------
// qk: [(s*B+b)*1024 + {0:Q, 512:K*c2} + h*64 + d]; vt: [b*512+h*64+d][s].
// S^T = mfma(K, Q): lane (g16,l16) owns q-row l16, kv = 16j + 4*g16 + r.
// RAW softmax in exp2 domain; scale pre-folded into K -> p = exp2(s) direct.
// l via ones-A MFMA. P roundtrips per-wave LDS (k32 layout, 54.5us-validated).
__global__ __launch_bounds__(512) void flash_all(
    const __hip_bfloat16* __restrict__ qkg, const __hip_bfloat16* __restrict__ vtg,
    __hip_bfloat16* __restrict__ outg,
    const __hip_bfloat16* __restrict__ qkl, const __hip_bfloat16* __restrict__ vtl,
    __hip_bfloat16* __restrict__ outl,
    const int* __restrict__ wptr, int S, int B, int blkoff)
{
  const int t = threadIdx.x, lane = t & 63, w = t >> 6;
  const int g16 = lane >> 4, l16 = lane & 15;
  const int gid = blockIdx.x + blkoff;
  const int isl = gid >= 512;
  const int id = gid & 511;
  const __hip_bfloat16* qk = isl ? qkl : qkg;
  const __hip_bfloat16* vt = isl ? vtl : vtg;
  __hip_bfloat16* outb = isl ? outl : outg;
  const int Wn = isl ? wptr[0] : S;
  const int xcd = id & 7, seq = id >> 3;
  const int bh = xcd + 8*(seq & 3);
  const int qt = seq >> 2;
  const int b = bh >> 3, h = bh & 7;
  const int q0 = qt * 128;
  const int kv0 = (q0 / Wn) * Wn;
  const int nkt = Wn >> 6;
  const int vtb = bh * 64;               // = b*512 + h*64

  __shared__ __attribute__((aligned(16))) __hip_bfloat16 Kb[2][64*64];
  __shared__ __attribute__((aligned(16))) __hip_bfloat16 Vb[2][64*64];
  __shared__ __attribute__((aligned(16))) short Pl[8][16*72];

  const int qrow = q0 + w*16 + l16;
  bf16x8 qa[2];
  {
    const __hip_bfloat16* qp = qk + ((long)qrow*B + b)*1024 + h*64 + g16*8;
    qa[0] = *(const bf16x8*)(const void*)qp;
    qa[1] = *(const bf16x8*)(const void*)(qp + 32);
  }
  bf16x8 aones;
#pragma unroll
  for (int e = 0; e < 8; ++e) aones[e] = (short)0x3F80;   // bf16 1.0

  f32x4 o[4] = {};
  f32x4 ol = {};

#define STAGE(tile, bufi)                                                      \
  {                                                                            \
    const int kvs_ = kv0 + (tile)*64;                                          \
    const int row_ = t >> 3;                                                   \
    const int sl_ = (t & 7) ^ (row_ & 7);                                      \
    gload_lds16(qk + ((long)(kvs_+row_)*B + b)*1024 + 512 + h*64 + sl_*8,      \
                (char*)&Kb[bufi][0] + t*16);                                   \
    gload_lds16(vt + (long)(vtb + row_)*2048 + kvs_ + sl_*8,                   \
                (char*)&Vb[bufi][0] + t*16);                                   \
  }

  STAGE(0, 0)

  for (int kt = 0; kt < nkt; ++kt) {
    const int cur = kt & 1;
    if (kt + 1 < nkt) {
      STAGE(kt + 1, cur ^ 1)
      asm volatile("s_waitcnt vmcnt(2)" ::: "memory");
    } else {
      asm volatile("s_waitcnt vmcnt(0)" ::: "memory");
    }
    __builtin_amdgcn_s_barrier();
    asm volatile("" ::: "memory");

    f32x4 s[4] = {};
    const char* Kp = (const char*)&Kb[cur][0];
    __builtin_amdgcn_s_setprio(1);
#pragma unroll
    for (int kk = 0; kk < 2; ++kk)
#pragma unroll
      for (int j = 0; j < 4; ++j) {
        const int row = j*16 + l16;
        const int slot = (kk*4 + g16) ^ (row & 7);
        bf16x8 kf = *(const bf16x8*)(Kp + row*128 + slot*16);
        s[j] = mfma16(kf, qa[kk], s[j]);
      }
    __builtin_amdgcn_s_setprio(0);

    short* Pw = &Pl[w][0];
#pragma unroll
    for (int j = 0; j < 4; ++j) {
      short4 pk4;
      pk4.x = (short)f2bf(__builtin_amdgcn_exp2f(s[j][0]));
      pk4.y = (short)f2bf(__builtin_amdgcn_exp2f(s[j][1]));
      pk4.z = (short)f2bf(__builtin_amdgcn_exp2f(s[j][2]));
      pk4.w = (short)f2bf(__builtin_amdgcn_exp2f(s[j][3]));
      *(short4*)(Pw + l16*72 + j*16 + g16*4) = pk4;
    }

    __builtin_amdgcn_s_setprio(1);
#pragma unroll
    for (int kk = 0; kk < 2; ++kk) {
      bf16x8 pf = *(const bf16x8*)(Pw + l16*72 + kk*32 + g16*8);
      ol = mfma16(aones, pf, ol);
#pragma unroll
      for (int dblk = 0; dblk < 4; ++dblk) {
        const int row = dblk*16 + l16;
        const int slot = (kk*4 + g16) ^ (row & 7);
        bf16x8 vf = *(const bf16x8*)((const char*)&Vb[cur][0] + row*128 + slot*16);
        o[dblk] = mfma16(vf, pf, o[dblk]);
      }
    }
    __builtin_amdgcn_s_setprio(0);

    asm volatile("" ::: "memory");
    __builtin_amdgcn_s_barrier();
  }

  const float inv = 1.f / ol[0];
  const long obase = ((long)qrow*B + b)*512 + h*64;
#pragma unroll
  for (int dblk = 0; dblk < 4; ++dblk) {
    ushort4 pk;
    pk.x = f2bf(o[dblk][0]*inv); pk.y = f2bf(o[dblk][1]*inv);
    pk.z = f2bf(o[dblk][2]*inv); pk.w = f2bf(o[dblk][3]*inv);
    *(ushort4*)(outb + obase + dblk*16 + g16*4) = pk;
  }
}

extern "C" void kernel_launch(void* const* d_in, const int* in_sizes, int n_in,
                              void* d_out, int out_size, void* d_ws, size_t ws_size,
                              hipStream_t stream) {
  const float* x   = (const float*)d_in[0];
  const float* wig = (const float*)d_in[1];
  const float* big = (const float*)d_in[2];
  const float* wog = (const float*)d_in[3];
  const float* bog = (const float*)d_in[4];
  const float* wil = (const float*)d_in[5];
  const float* bil = (const float*)d_in[6];
  const float* wol = (const float*)d_in[7];
  const float* bol = (const float*)d_in[8];
  const int*   wsz = (const int*)d_in[9];

  char* ws = (char*)d_ws;
  __hip_bfloat16* xb    = (__hip_bfloat16*)(ws + 0);          // 8 MB (-> attn_g)
  __hip_bfloat16* wigb  = (__hip_bfloat16*)(ws + 8388608);
  __hip_bfloat16* wilb  = (__hip_bfloat16*)(ws + 9961472);
  __hip_bfloat16* wogb  = (__hip_bfloat16*)(ws + 11534336);
  __hip_bfloat16* wolb  = (__hip_bfloat16*)(ws + 12058624);
  __hip_bfloat16* qkg   = (__hip_bfloat16*)(ws + 12582912);   // 16 MB
  __hip_bfloat16* qkl   = (__hip_bfloat16*)(ws + 29360128);   // 16 MB
  __hip_bfloat16* vtg   = (__hip_bfloat16*)(ws + 46137344);   // 8 MB
  __hip_bfloat16* vtl   = (__hip_bfloat16*)(ws + 54525952);   // 8 MB (end 60 MB)
  __hip_bfloat16* attng = xb;                                  // xb dead after qkv

  const int big_ws = ws_size >= (size_t)71303168;              // 68 MB
  __hip_bfloat16* attnl = big_ws ? (__hip_bfloat16*)(ws + 62914560)
                                 : qkg;                        // fallback alias

  convert_all<<<6144, 256, 0, stream>>>(
      (const float4*)x, (const float4*)wig, (const float4*)wil,
      (const float4*)wog, (const float4*)wol, (ushort4*)ws);

  gemm_qkv<<<1536, 512, 0, stream>>>(xb, wigb, big, wilb, bil,
                                     qkg, vtg, qkl, vtl, 8192, 1536, 512);

  if (big_ws) {
    flash_all<<<1024, 512, 0, stream>>>(qkg, vtg, attng, qkl, vtl, attnl,
                                        wsz, 2048, 4, 0);
  } else {
    flash_all<<<512, 512, 0, stream>>>(qkg, vtg, attng, qkl, vtl, attnl,
                                       wsz, 2048, 4, 0);
    flash_all<<<512, 512, 0, stream>>>(qkg, vtg, attng, qkl, vtl, attnl,
                                       wsz, 2048, 4, 512);
  }

  gemm_out<<<1024, 512, 0, stream>>>(attng, wogb, bog, attnl, wolb, bol,
                                     (float*)d_out, 8192, 512, 512);
}